// Round 8
// baseline (232.407 us; speedup 1.0000x reference)
//
#include <hip/hip_runtime.h>
#include <hip/hip_bf16.h>
#include <math.h>

// Problem constants (MambaBlock: D_MODEL=1024, D_STATE=16, D_CONV=4, EXPAND=2, DT_RANK=64)
#define NB      2
#define LSEQ    2048
#define BLTOK   4096      // NB * LSEQ
#define DM      1024
#define DI      2048      // EXPAND * DM
#define NST     16
#define DTR     64
#define CH      64        // scan chunks
#define LC      32        // LSEQ / CH
#define LOG2E   1.44269504f

typedef __attribute__((ext_vector_type(8))) short short8;
typedef __attribute__((ext_vector_type(4))) float f32x4;

#define LDS_PTR(p) ((__attribute__((address_space(3))) void*)(p))
#define GLB_PTR(p) ((const __attribute__((address_space(1))) void*)(p))

static __device__ __forceinline__ unsigned short f2bf(float f) {
    unsigned int u = __float_as_uint(f);
    unsigned int r = (u + 0x7FFFu + ((u >> 16) & 1u)) >> 16;   // RNE
    return (unsigned short)r;
}
static __device__ __forceinline__ float bf2f(unsigned short v) {
    return __uint_as_float((unsigned int)v << 16);
}

// w^(n+1) for n=0..15 via binary tree (depth 4, 15 full-rate muls)
static __device__ __forceinline__ void pow_tree(float w, float* e) {
    e[0]  = w;
    e[1]  = e[0] * e[0];
    e[2]  = e[1] * e[0];
    e[3]  = e[1] * e[1];
    e[4]  = e[3] * e[0];
    e[5]  = e[3] * e[1];
    e[6]  = e[3] * e[2];
    e[7]  = e[3] * e[3];
    e[8]  = e[7] * e[0];
    e[9]  = e[7] * e[1];
    e[10] = e[7] * e[2];
    e[11] = e[7] * e[3];
    e[12] = e[7] * e[4];
    e[13] = e[7] * e[5];
    e[14] = e[7] * e[6];
    e[15] = e[7] * e[7];
}

// ---------------------------------------------------------------------------
// Fused fp32 -> bf16 cast of all 5 weight/activation tensors (one launch).
// ---------------------------------------------------------------------------
#define C4_X   (BLTOK * DM / 4)
#define C4_W1  (2 * DI * DM / 4)
#define C4_W3  (96 * DI / 4)
#define C4_W6  (DM * DI / 4)
#define C4_W5  (DI * DTR / 4)
#define C4_TOT (C4_X + C4_W1 + C4_W3 + C4_W6 + C4_W5)

__launch_bounds__(256)
__global__ void cast_all(const float* __restrict__ x,   unsigned short* __restrict__ xb,
                         const float* __restrict__ w1,  unsigned short* __restrict__ wb1,
                         const float* __restrict__ w3,  unsigned short* __restrict__ wb3,
                         const float* __restrict__ w6,  unsigned short* __restrict__ wb6,
                         const float* __restrict__ w5,  unsigned short* __restrict__ wb5)
{
    int i = blockIdx.x * 256 + threadIdx.x;
    if (i >= C4_TOT) return;
    const float* in; unsigned short* out;
    if (i < C4_X)                         { in = x;  out = xb;  }
    else if ((i -= C4_X) < C4_W1)         { in = w1; out = wb1; }
    else if ((i -= C4_W1) < C4_W3)        { in = w3; out = wb3; }
    else if ((i -= C4_W3) < C4_W6)        { in = w6; out = wb6; }
    else       { i -= C4_W6;                in = w5; out = wb5; }
    float4 v = ((const float4*)in)[i];
    uint2 o;
    o.x = (unsigned)f2bf(v.x) | ((unsigned)f2bf(v.y) << 16);
    o.y = (unsigned)f2bf(v.z) | ((unsigned)f2bf(v.w) << 16);
    ((uint2*)out)[i] = o;
}

// ---------------------------------------------------------------------------
// bf16 MFMA GEMM, 128x128 tile, BK=64 double-buffered 2-phase pipeline.
// LDS XOR swizzle (both-sides). M,N mult of 128, K mult of 64.
// EPI 0: fp32 C.  EPI 1: bf16 C.  EPI 3: bf16 softplus(acc+bias[col]).
// ---------------------------------------------------------------------------
template<int EPI>
__launch_bounds__(256)
__global__ void gemm_db(const unsigned short* __restrict__ A,
                        const unsigned short* __restrict__ W,
                        void* __restrict__ Cout,
                        const float* __restrict__ bias,
                        int M, int N, int K, int lda, int ldb, int ldc)
{
    __shared__ unsigned short lds[2][2][128 * 64];   // 64 KB

    const int tid = threadIdx.x;
    const int l = tid & 63;
    const int w = tid >> 6;
    const int wr = w >> 1, wc = w & 1;
    const int brow = blockIdx.y * 128;
    const int bcol = blockIdx.x * 128;

    const int strow = tid >> 3;                          // 0..31
    const int scol  = ((tid & 7) ^ (strow & 7)) * 8;     // swizzled source col

    f32x4 acc[4][4];
#pragma unroll
    for (int i = 0; i < 4; ++i)
#pragma unroll
        for (int j = 0; j < 4; ++j) acc[i][j] = (f32x4)0.f;

    auto stage = [&](int bb, int k0) {
#pragma unroll
        for (int i = 0; i < 4; ++i) {
            const unsigned short* ga = A + (size_t)(brow + i * 32 + strow) * lda + k0 + scol;
            __builtin_amdgcn_global_load_lds(GLB_PTR(ga),
                LDS_PTR((char*)&lds[bb][0][0] + (i * 32 + w * 8) * 128), 16, 0, 0);
            const unsigned short* gb = W + (size_t)(bcol + i * 32 + strow) * ldb + k0 + scol;
            __builtin_amdgcn_global_load_lds(GLB_PTR(gb),
                LDS_PTR((char*)&lds[bb][1][0] + (i * 32 + w * 8) * 128), 16, 0, 0);
        }
    };

    auto compute = [&](int bb) {
        const char* baseA = (const char*)&lds[bb][0][0];
        const char* baseB = (const char*)&lds[bb][1][0];
        const int xo  = (l & 7) * 16;
        const int ko0 = (l >> 4) * 16;
#pragma unroll
        for (int ks = 0; ks < 2; ++ks) {
            const int kb = ks * 64 + ko0;
            short8 af[4], bfr[4];
#pragma unroll
            for (int i = 0; i < 4; ++i) {
                const int rowA = wr * 64 + i * 16 + (l & 15);
                af[i] = *(const short8*)(baseA + rowA * 128 + (kb ^ xo));
                const int rowB = wc * 64 + i * 16 + (l & 15);
                bfr[i] = *(const short8*)(baseB + rowB * 128 + (kb ^ xo));
            }
#pragma unroll
            for (int i = 0; i < 4; ++i)
#pragma unroll
                for (int j = 0; j < 4; ++j)
                    acc[i][j] = __builtin_amdgcn_mfma_f32_16x16x32_bf16(af[i], bfr[j], acc[i][j], 0, 0, 0);
        }
    };

    const int nt = K / 64;
    stage(0, 0);
    __syncthreads();
    int cur = 0;
    for (int t = 0; t < nt - 1; ++t) {
        stage(cur ^ 1, (t + 1) * 64);
        compute(cur);
        __syncthreads();
        cur ^= 1;
    }
    compute(cur);

#pragma unroll
    for (int i = 0; i < 4; ++i) {
        const int row0 = brow + wr * 64 + i * 16 + ((l >> 4) * 4);
#pragma unroll
        for (int j = 0; j < 4; ++j) {
            const int col = bcol + wc * 64 + j * 16 + (l & 15);
            if (EPI == 1) {
                unsigned short* Cb = (unsigned short*)Cout;
#pragma unroll
                for (int r = 0; r < 4; ++r)
                    Cb[(size_t)(row0 + r) * ldc + col] = f2bf(acc[i][j][r]);
            } else if (EPI == 3) {
                const float bv = bias[col];
#pragma unroll
                for (int r = 0; r < 4; ++r) {
                    float v = acc[i][j][r] + bv;
                    v = (v > 20.f) ? v : log1pf(__expf(v));
                    ((unsigned short*)Cout)[(size_t)(row0 + r) * ldc + col] = f2bf(v);
                }
            } else {
                float* Cf = (float*)Cout;
#pragma unroll
                for (int r = 0; r < 4; ++r)
                    Cf[(size_t)(row0 + r) * ldc + col] = acc[i][j][r];
            }
        }
    }
}

// ---------------------------------------------------------------------------
// 64x128-tile variant (for skinny-N GEMMs): waves 1x4, each 64x32, acc[4][2].
// LDS 48 KB -> 3 blocks/CU capacity; doubles block count vs 128x128.
// fp32 C output.
// ---------------------------------------------------------------------------
__launch_bounds__(256)
__global__ void gemm_db64(const unsigned short* __restrict__ A,
                          const unsigned short* __restrict__ W,
                          float* __restrict__ Cout,
                          int M, int N, int K, int lda, int ldb, int ldc)
{
    __shared__ unsigned short ldsA[2][64 * 64];    // 2 x 8 KB
    __shared__ unsigned short ldsB[2][128 * 64];   // 2 x 16 KB

    const int tid = threadIdx.x;
    const int l = tid & 63;
    const int w = tid >> 6;                       // wave 0..3 -> col block
    const int brow = blockIdx.y * 64;
    const int bcol = blockIdx.x * 128;

    const int strow = tid >> 3;                   // 0..31
    const int scol  = ((tid & 7) ^ (strow & 7)) * 8;

    f32x4 acc[4][2];
#pragma unroll
    for (int i = 0; i < 4; ++i)
#pragma unroll
        for (int j = 0; j < 2; ++j) acc[i][j] = (f32x4)0.f;

    auto stage = [&](int bb, int k0) {
#pragma unroll
        for (int i = 0; i < 2; ++i) {
            const unsigned short* ga = A + (size_t)(brow + i * 32 + strow) * lda + k0 + scol;
            __builtin_amdgcn_global_load_lds(GLB_PTR(ga),
                LDS_PTR((char*)&ldsA[bb][0] + (i * 32 + w * 8) * 128), 16, 0, 0);
        }
#pragma unroll
        for (int i = 0; i < 4; ++i) {
            const unsigned short* gb = W + (size_t)(bcol + i * 32 + strow) * ldb + k0 + scol;
            __builtin_amdgcn_global_load_lds(GLB_PTR(gb),
                LDS_PTR((char*)&ldsB[bb][0] + (i * 32 + w * 8) * 128), 16, 0, 0);
        }
    };

    auto compute = [&](int bb) {
        const char* baseA = (const char*)&ldsA[bb][0];
        const char* baseB = (const char*)&ldsB[bb][0];
        const int xo  = (l & 7) * 16;
        const int ko0 = (l >> 4) * 16;
#pragma unroll
        for (int ks = 0; ks < 2; ++ks) {
            const int kb = ks * 64 + ko0;
            short8 af[4], bfr[2];
#pragma unroll
            for (int i = 0; i < 4; ++i) {
                const int rowA = i * 16 + (l & 15);
                af[i] = *(const short8*)(baseA + rowA * 128 + (kb ^ xo));
            }
#pragma unroll
            for (int j = 0; j < 2; ++j) {
                const int rowB = w * 32 + j * 16 + (l & 15);
                bfr[j] = *(const short8*)(baseB + rowB * 128 + (kb ^ xo));
            }
#pragma unroll
            for (int i = 0; i < 4; ++i)
#pragma unroll
                for (int j = 0; j < 2; ++j)
                    acc[i][j] = __builtin_amdgcn_mfma_f32_16x16x32_bf16(af[i], bfr[j], acc[i][j], 0, 0, 0);
        }
    };

    const int nt = K / 64;
    stage(0, 0);
    __syncthreads();
    int cur = 0;
    for (int t = 0; t < nt - 1; ++t) {
        stage(cur ^ 1, (t + 1) * 64);
        compute(cur);
        __syncthreads();
        cur ^= 1;
    }
    compute(cur);

#pragma unroll
    for (int i = 0; i < 4; ++i) {
        const int row0 = brow + i * 16 + ((l >> 4) * 4);
#pragma unroll
        for (int j = 0; j < 2; ++j) {
            const int col = bcol + w * 32 + j * 16 + (l & 15);
#pragma unroll
            for (int r = 0; r < 4; ++r)
                Cout[(size_t)(row0 + r) * ldc + col] = acc[i][j][r];
        }
    }
}

// ---------------------------------------------------------------------------
// Split-K MFMA GEMM for x_proj (N=96): blockIdx.z = k-slice, partial C out.
// ---------------------------------------------------------------------------
__launch_bounds__(256)
__global__ void gemm_mfma_sk(const unsigned short* __restrict__ A,
                             const unsigned short* __restrict__ W,
                             float* __restrict__ Cpart,
                             int M, int N, int K, int lda, int ldb, int ldc, int kslices)
{
    __shared__ unsigned short Asub[128 * 32];
    __shared__ unsigned short Bsub[128 * 32];

    const int tid = threadIdx.x;
    const int l = tid & 63;
    const int w = tid >> 6;
    const int wr = w >> 1, wc = w & 1;
    const int brow = blockIdx.y * 128;
    const int bcol = blockIdx.x * 128;
    const int ks = blockIdx.z;
    const int klen = K / kslices;
    const int kbeg = ks * klen;
    float* C = Cpart + (size_t)ks * M * ldc;

    f32x4 acc[4][4];
#pragma unroll
    for (int i = 0; i < 4; ++i)
#pragma unroll
        for (int j = 0; j < 4; ++j) acc[i][j] = (f32x4)0.f;

    const int srow = tid >> 2;
    const int scol = (tid & 3) * 8;

    for (int k0 = kbeg; k0 < kbeg + klen; k0 += 32) {
#pragma unroll
        for (int i = 0; i < 2; ++i) {
            const int ar = brow + i * 64 + srow;
            const unsigned short* ga = A + (size_t)ar * lda + k0 + scol;
            __builtin_amdgcn_global_load_lds(GLB_PTR(ga),
                LDS_PTR((char*)Asub + i * 4096 + w * 1024), 16, 0, 0);
            int nr = bcol + i * 64 + srow;
            if (nr > N - 1) nr = N - 1;
            const unsigned short* gb = W + (size_t)nr * ldb + k0 + scol;
            __builtin_amdgcn_global_load_lds(GLB_PTR(gb),
                LDS_PTR((char*)Bsub + i * 4096 + w * 1024), 16, 0, 0);
        }
        __syncthreads();

        short8 af[4], bf[4];
#pragma unroll
        for (int i = 0; i < 4; ++i) {
            const int row = wr * 64 + i * 16 + (l & 15);
            af[i] = *(const short8*)((const char*)Asub + row * 64 + (l >> 4) * 16);
        }
#pragma unroll
        for (int j = 0; j < 4; ++j) {
            const int row = wc * 64 + j * 16 + (l & 15);
            bf[j] = *(const short8*)((const char*)Bsub + row * 64 + (l >> 4) * 16);
        }
#pragma unroll
        for (int i = 0; i < 4; ++i)
#pragma unroll
            for (int j = 0; j < 4; ++j)
                acc[i][j] = __builtin_amdgcn_mfma_f32_16x16x32_bf16(af[i], bf[j], acc[i][j], 0, 0, 0);
        __syncthreads();
    }

#pragma unroll
    for (int i = 0; i < 4; ++i) {
        const int row0 = brow + wr * 64 + i * 16 + ((l >> 4) * 4);
#pragma unroll
        for (int j = 0; j < 4; ++j) {
            const int col = bcol + wc * 64 + j * 16 + (l & 15);
            if (col < N) {
#pragma unroll
                for (int r = 0; r < 4; ++r)
                    C[(size_t)(row0 + r) * ldc + col] = acc[i][j][r];
            }
        }
    }
}

// sum partial slices -> xdbl (fp32) + compact bf16 copy of dt cols [0,64)
__launch_bounds__(256)
__global__ void sk_reduce(const float* __restrict__ part, float* __restrict__ out,
                          unsigned short* __restrict__ dtb, int n4, int slices)
{
    int i = blockIdx.x * 256 + threadIdx.x;
    if (i < n4) {
        float4 s = ((const float4*)part)[i];
        for (int k = 1; k < slices; ++k) {
            float4 p = ((const float4*)part)[(size_t)k * n4 + i];
            s.x += p.x; s.y += p.y; s.z += p.z; s.w += p.w;
        }
        ((float4*)out)[i] = s;
        const int r = i / 24, cq = i % 24;
        if (cq < 16) {
            uint2 o;
            o.x = (unsigned)f2bf(s.x) | ((unsigned)f2bf(s.y) << 16);
            o.y = (unsigned)f2bf(s.z) | ((unsigned)f2bf(s.w) << 16);
            *(uint2*)&dtb[(size_t)r * DTR + cq * 4] = o;
        }
    }
}

// ---------------------------------------------------------------------------
// Causal depthwise conv1d (width 4) + bias + silu.  bf16 in/out.
// ---------------------------------------------------------------------------
__launch_bounds__(256)
__global__ void conv_silu_kernel(const unsigned short* __restrict__ xzb,
                                 const float* __restrict__ cw,
                                 const float* __restrict__ cb,
                                 unsigned short* __restrict__ ub)
{
    const int orig = blockIdx.x;
    const int bl = (orig & 7) * (BLTOK / 8) + (orig >> 3);   // bijective (4096%8==0)
    const int l  = bl & (LSEQ - 1);
    const int d0 = threadIdx.x * 8;

    float acc[8];
    float4 w4[8];
#pragma unroll
    for (int q = 0; q < 8; ++q) {
        w4[q]  = *(const float4*)&cw[(d0 + q) * 4];
        acc[q] = cb[d0 + q];
    }
#pragma unroll
    for (int k = 0; k < 4; ++k) {
        const int ls = l - 3 + k;
        if (ls < 0) continue;
        short8 v = *(const short8*)&xzb[(size_t)(bl - 3 + k) * (2 * DI) + d0];
#pragma unroll
        for (int q = 0; q < 8; ++q) {
            const float wk = ((const float*)&w4[q])[k];
            acc[q] = fmaf(wk, bf2f((unsigned short)v[q]), acc[q]);
        }
    }
    short8 o;
#pragma unroll
    for (int q = 0; q < 8; ++q) {
        const float s = acc[q] / (1.f + __expf(-acc[q]));
        o[q] = (short)f2bf(s);
    }
    *(short8*)&ub[(size_t)bl * DI + d0] = o;
}

// ---------------------------------------------------------------------------
// Scan phase 1: per chunk, per (b,d): 16 n-states in registers.
// delta bf16; S4D fast path (dA[n] = w^(n+1)); stores S + dsum (no P).
// ---------------------------------------------------------------------------
__launch_bounds__(256)
__global__ void scan_phase1(const unsigned short* __restrict__ delta,
                            const unsigned short* __restrict__ ub,
                            const float* __restrict__ xdbl, const float* __restrict__ A_log,
                            float* __restrict__ S, float* __restrict__ dsum_out)
{
    __shared__ float sB[LC][NST];
    const int tid = threadIdx.x;
    const int d = blockIdx.x * 256 + tid;
    const int c = blockIdx.y;
    const int b = blockIdx.z;
    const int t0 = c * LC;

    for (int i = tid; i < LC * NST; i += 256)
        sB[i >> 4][i & 15] = xdbl[(size_t)(b * LSEQ + t0 + (i >> 4)) * 96 + 64 + (i & 15)];
    __syncthreads();

    const float Av0 = -__expf(A_log[d * NST]) * LOG2E;
    bool fast = true;
    for (int n = 1; n < NST; ++n) {
        const float avn = -__expf(A_log[d * NST + n]) * LOG2E;
        fast &= (fabsf(avn - (float)(n + 1) * Av0) <= 1e-3f * fabsf(avn));
    }

    float Sv[NST];
    float dsum = 0.f;
#pragma unroll
    for (int n = 0; n < NST; ++n) Sv[n] = 0.f;

    const unsigned short* dbase = delta + (size_t)(b * LSEQ + t0) * DI + d;
    const unsigned short* ubase = ub    + (size_t)(b * LSEQ + t0) * DI + d;

    if (fast) {
        for (int tg = 0; tg < LC; tg += 4) {
            float dl[4], uu[4];
#pragma unroll
            for (int q = 0; q < 4; ++q) {
                dl[q] = bf2f(dbase[(size_t)(tg + q) * DI]);
                uu[q] = bf2f(ubase[(size_t)(tg + q) * DI]);
            }
#pragma unroll
            for (int q = 0; q < 4; ++q) {
                const float du = dl[q] * uu[q];
                dsum += dl[q];
                float e[NST];
                pow_tree(__builtin_amdgcn_exp2f(dl[q] * Av0), e);
#pragma unroll
                for (int n = 0; n < NST; ++n)
                    Sv[n] = fmaf(e[n], Sv[n], du * sB[tg + q][n]);
            }
        }
    } else {
        for (int t = 0; t < LC; ++t) {
            const float dlt = bf2f(dbase[(size_t)t * DI]);
            const float uu  = bf2f(ubase[(size_t)t * DI]);
            const float du  = dlt * uu;
            dsum += dlt;
            for (int n = 0; n < NST; ++n) {
                const float avn = -__expf(A_log[d * NST + n]) * LOG2E;
                const float dA = __builtin_amdgcn_exp2f(dlt * avn);
                Sv[n] = fmaf(dA, Sv[n], du * sB[t][n]);
            }
        }
    }

    const size_t base = ((size_t)(b * CH + c) * DI + d) * NST;
#pragma unroll
    for (int n = 0; n < NST; n += 4)
        *(f32x4*)&S[base + n] = (f32x4){Sv[n], Sv[n+1], Sv[n+2], Sv[n+3]};
    dsum_out[(size_t)(b * CH + c) * DI + d] = dsum;
}

// ---------------------------------------------------------------------------
// Scan phase 2: sequential combine over chunks; recompute P from dsum.
// ---------------------------------------------------------------------------
__launch_bounds__(256)
__global__ void scan_phase2(const float* __restrict__ S, const float* __restrict__ dsum,
                            const float* __restrict__ A_log, float* __restrict__ hin)
{
    const int g = blockIdx.x * 256 + threadIdx.x;
    const int n = g & 15;
    const int d = (g >> 4) & (DI - 1);
    const int b = g >> 15;
    const float avn = -__expf(A_log[d * NST + n]) * LOG2E;
    float h = 0.f;
    for (int c = 0; c < CH; ++c) {
        const size_t idx = ((size_t)(b * CH + c) * DI + d) * NST + n;
        hin[idx] = h;
        const float Pc = __builtin_amdgcn_exp2f(dsum[(size_t)(b * CH + c) * DI + d] * avn);
        h = fmaf(Pc, h, S[idx]);
    }
}

// ---------------------------------------------------------------------------
// Scan phase 3: replay chunk with h_in; fuse D-skip + silu(z) gating; bf16 out.
// ---------------------------------------------------------------------------
__launch_bounds__(256)
__global__ void scan_phase3(const unsigned short* __restrict__ delta,
                            const unsigned short* __restrict__ ub,
                            const float* __restrict__ xdbl, const float* __restrict__ A_log,
                            const float* __restrict__ Dskip, const unsigned short* __restrict__ xzb,
                            const float* __restrict__ hin, unsigned short* __restrict__ yg)
{
    __shared__ float sB[LC][NST], sC[LC][NST];
    const int tid = threadIdx.x;
    const int d = blockIdx.x * 256 + tid;
    const int c = blockIdx.y;
    const int b = blockIdx.z;
    const int t0 = c * LC;

    for (int i = tid; i < LC * NST; i += 256) {
        const size_t row = (size_t)(b * LSEQ + t0 + (i >> 4)) * 96;
        sB[i >> 4][i & 15] = xdbl[row + 64 + (i & 15)];
        sC[i >> 4][i & 15] = xdbl[row + 80 + (i & 15)];
    }
    __syncthreads();

    const float Av0 = -__expf(A_log[d * NST]) * LOG2E;
    bool fast = true;
    for (int n = 1; n < NST; ++n) {
        const float avn = -__expf(A_log[d * NST + n]) * LOG2E;
        fast &= (fabsf(avn - (float)(n + 1) * Av0) <= 1e-3f * fabsf(avn));
    }

    float h[NST];
    const size_t hbase = ((size_t)(b * CH + c) * DI + d) * NST;
#pragma unroll
    for (int n = 0; n < NST; n += 4) {
        f32x4 t = *(const f32x4*)&hin[hbase + n];
        h[n] = t.x; h[n+1] = t.y; h[n+2] = t.z; h[n+3] = t.w;
    }
    const float Dskv = Dskip[d];

    const unsigned short* dbase = delta + (size_t)(b * LSEQ + t0) * DI + d;
    const unsigned short* ubase = ub    + (size_t)(b * LSEQ + t0) * DI + d;
    const unsigned short* zbase = xzb   + (size_t)(b * LSEQ + t0) * (2 * DI) + DI + d;
    unsigned short* yrow = yg + (size_t)(b * LSEQ + t0) * DI + d;

    if (fast) {
        for (int tg = 0; tg < LC; tg += 4) {
            float dl[4], uu[4], zz[4];
#pragma unroll
            for (int q = 0; q < 4; ++q) {
                dl[q] = bf2f(dbase[(size_t)(tg + q) * DI]);
                uu[q] = bf2f(ubase[(size_t)(tg + q) * DI]);
                zz[q] = bf2f(zbase[(size_t)(tg + q) * (2 * DI)]);
            }
#pragma unroll
            for (int q = 0; q < 4; ++q) {
                const float du = dl[q] * uu[q];
                float e[NST];
                pow_tree(__builtin_amdgcn_exp2f(dl[q] * Av0), e);
                float y = 0.f;
#pragma unroll
                for (int n = 0; n < NST; ++n) {
                    h[n] = fmaf(e[n], h[n], du * sB[tg + q][n]);
                    y = fmaf(h[n], sC[tg + q][n], y);
                }
                const float zv = zz[q];
                const float sig = __frcp_rn(1.f + __expf(-zv));
                const float val = (y + uu[q] * Dskv) * (zv * sig);
                yrow[(size_t)(tg + q) * DI] = f2bf(val);
            }
        }
    } else {
        for (int t = 0; t < LC; ++t) {
            const float dlt = bf2f(dbase[(size_t)t * DI]);
            const float uu  = bf2f(ubase[(size_t)t * DI]);
            const float zv  = bf2f(zbase[(size_t)t * (2 * DI)]);
            const float du  = dlt * uu;
            float y = 0.f;
            for (int n = 0; n < NST; ++n) {
                const float avn = -__expf(A_log[d * NST + n]) * LOG2E;
                const float dA = __builtin_amdgcn_exp2f(dlt * avn);
                h[n] = fmaf(dA, h[n], du * sB[t][n]);
                y = fmaf(h[n], sC[t][n], y);
            }
            const float sig = __frcp_rn(1.f + __expf(-zv));
            const float val = (y + uu * Dskv) * (zv * sig);
            yrow[(size_t)t * DI] = f2bf(val);
        }
    }
}

// ---------------------------------------------------------------------------
extern "C" void kernel_launch(void* const* d_in, const int* in_sizes, int n_in,
                              void* d_out, int out_size, void* d_ws, size_t ws_size,
                              hipStream_t stream)
{
    const float* x        = (const float*)d_in[0];
    const float* in_w     = (const float*)d_in[1];
    const float* conv_w   = (const float*)d_in[2];
    const float* conv_b   = (const float*)d_in[3];
    const float* xproj_w  = (const float*)d_in[4];
    const float* dtproj_w = (const float*)d_in[5];
    const float* dtproj_b = (const float*)d_in[6];
    const float* A_log    = (const float*)d_in[7];
    const float* Dskip    = (const float*)d_in[8];
    const float* out_w    = (const float*)d_in[9];
    float* out = (float*)d_out;

    char* ws = (char*)d_ws;
#define MB(x) ((size_t)(x) * 1024 * 1024)
    unsigned short* xzb   = (unsigned short*)(ws);           // bf16 [4096,4096] 32 MB
    unsigned short* ub    = (unsigned short*)(ws + MB(32));  // bf16 [4096,2048] 16 MB
    unsigned short* delta = (unsigned short*)(ws + MB(48));  // bf16 [4096,2048] 16 MB
    float*          xdbl  = (float*)(ws + MB(64));           // fp32 [4096,96]  1.5 MB
    unsigned short* ygb   = (unsigned short*)(ws + MB(66));  // bf16 [4096,2048] 16 MB
    float*          S     = (float*)(ws + MB(82));           // 16 MB (also x_proj partials)
    float*          dsum  = (float*)(ws + MB(98));           // 1 MB
    float*          hin   = (float*)(ws + MB(99));           // 16 MB
    unsigned short* xb    = (unsigned short*)(ws + MB(115)); // bf16 x      8 MB
    unsigned short* wb1   = (unsigned short*)(ws + MB(123)); // bf16 in_w   8 MB
    unsigned short* wb3   = (unsigned short*)(ws + MB(131)); // bf16 xproj  0.4 MB
    unsigned short* wb6   = (unsigned short*)(ws + MB(132)); // bf16 out_w  4 MB
    unsigned short* wb5   = (unsigned short*)(ws + MB(136)); // bf16 dtproj_w 0.25 MB
    unsigned short* dtb   = (unsigned short*)(ws + MB(137)); // bf16 dt [4096,64] 0.5 MB
    float*          xdbl_part = S;                           // 8 x [4096,96]

    dim3 blk(256);

    // 0) all fp32->bf16 casts in one launch
    cast_all<<<dim3((C4_TOT + 255) / 256), blk, 0, stream>>>(x, xb, in_w, wb1, xproj_w, wb3,
                                                             out_w, wb6, dtproj_w, wb5);

    // 1) in_proj: xzb = bf16(x @ in_w^T)   [4096 x 4096], K=1024
    gemm_db<1><<<dim3(32, 32), blk, 0, stream>>>(xb, wb1, xzb, nullptr,
                                                 BLTOK, 2 * DI, DM, DM, DM, 2 * DI);

    // 2) conv + silu -> ub (bf16)
    conv_silu_kernel<<<dim3(BLTOK), blk, 0, stream>>>(xzb, conv_w, conv_b, ub);

    // 3) x_proj split-K=8: partials then reduce (fp32 xdbl + bf16 dt copy)
    gemm_mfma_sk<<<dim3(1, 32, 8), blk, 0, stream>>>(ub, wb3, xdbl_part,
                                                     BLTOK, DTR + 2 * NST, DI, DI, DI, 96, 8);
    sk_reduce<<<dim3((BLTOK * 96 / 4 + 255) / 256), blk, 0, stream>>>(xdbl_part, xdbl, dtb,
                                                                      BLTOK * 96 / 4, 8);

    // 4) dt_proj + softplus -> bf16 delta  [4096 x 2048], K=64 (MFMA)
    gemm_db<3><<<dim3(16, 32), blk, 0, stream>>>(dtb, wb5, delta, dtproj_b,
                                                 BLTOK, DI, DTR, DTR, DTR, DI);

    // 5) chunked selective scan (CH=64, LC=32; P replaced by dsum)
    scan_phase1<<<dim3(DI / 256, CH, NB), blk, 0, stream>>>(delta, ub, xdbl, A_log, S, dsum);
    scan_phase2<<<dim3(NB * DI * NST / 256), blk, 0, stream>>>(S, dsum, A_log, hin);
    scan_phase3<<<dim3(DI / 256, CH, NB), blk, 0, stream>>>(delta, ub, xdbl, A_log, Dskip,
                                                            xzb, hin, ygb);

    // 6) out_proj: out = yg @ out_w^T   [4096 x 1024], K=2048  (64x128 tile, 512 blocks)
    gemm_db64<<<dim3(8, 64), blk, 0, stream>>>(ygb, wb6, out, BLTOK, DM, DI, DI, DI, DM);
}

// Round 9
// 228.907 us; speedup vs baseline: 1.0153x; 1.0153x over previous
//
#include <hip/hip_runtime.h>
#include <hip/hip_bf16.h>
#include <math.h>

// Problem constants (MambaBlock: D_MODEL=1024, D_STATE=16, D_CONV=4, EXPAND=2, DT_RANK=64)
#define NB      2
#define LSEQ    2048
#define BLTOK   4096      // NB * LSEQ
#define DM      1024
#define DI      2048      // EXPAND * DM
#define NST     16
#define DTR     64
#define CH      64        // scan chunks
#define LC      32        // LSEQ / CH
#define LOG2E   1.44269504f

typedef __attribute__((ext_vector_type(8))) short short8;
typedef __attribute__((ext_vector_type(4))) float f32x4;

#define LDS_PTR(p) ((__attribute__((address_space(3))) void*)(p))
#define GLB_PTR(p) ((const __attribute__((address_space(1))) void*)(p))

static __device__ __forceinline__ unsigned short f2bf(float f) {
    unsigned int u = __float_as_uint(f);
    unsigned int r = (u + 0x7FFFu + ((u >> 16) & 1u)) >> 16;   // RNE
    return (unsigned short)r;
}
static __device__ __forceinline__ float bf2f(unsigned short v) {
    return __uint_as_float((unsigned int)v << 16);
}

// w^(n+1) for n=0..15 via binary tree (depth 4, 15 full-rate muls)
static __device__ __forceinline__ void pow_tree(float w, float* e) {
    e[0]  = w;
    e[1]  = e[0] * e[0];
    e[2]  = e[1] * e[0];
    e[3]  = e[1] * e[1];
    e[4]  = e[3] * e[0];
    e[5]  = e[3] * e[1];
    e[6]  = e[3] * e[2];
    e[7]  = e[3] * e[3];
    e[8]  = e[7] * e[0];
    e[9]  = e[7] * e[1];
    e[10] = e[7] * e[2];
    e[11] = e[7] * e[3];
    e[12] = e[7] * e[4];
    e[13] = e[7] * e[5];
    e[14] = e[7] * e[6];
    e[15] = e[7] * e[7];
}

// ---------------------------------------------------------------------------
// Fused fp32 -> bf16 cast of all 5 weight/activation tensors (one launch).
// ---------------------------------------------------------------------------
#define C4_X   (BLTOK * DM / 4)
#define C4_W1  (2 * DI * DM / 4)
#define C4_W3  (96 * DI / 4)
#define C4_W6  (DM * DI / 4)
#define C4_W5  (DI * DTR / 4)
#define C4_TOT (C4_X + C4_W1 + C4_W3 + C4_W6 + C4_W5)

__launch_bounds__(256)
__global__ void cast_all(const float* __restrict__ x,   unsigned short* __restrict__ xb,
                         const float* __restrict__ w1,  unsigned short* __restrict__ wb1,
                         const float* __restrict__ w3,  unsigned short* __restrict__ wb3,
                         const float* __restrict__ w6,  unsigned short* __restrict__ wb6,
                         const float* __restrict__ w5,  unsigned short* __restrict__ wb5)
{
    int i = blockIdx.x * 256 + threadIdx.x;
    if (i >= C4_TOT) return;
    const float* in; unsigned short* out;
    if (i < C4_X)                         { in = x;  out = xb;  }
    else if ((i -= C4_X) < C4_W1)         { in = w1; out = wb1; }
    else if ((i -= C4_W1) < C4_W3)        { in = w3; out = wb3; }
    else if ((i -= C4_W3) < C4_W6)        { in = w6; out = wb6; }
    else       { i -= C4_W6;                in = w5; out = wb5; }
    float4 v = ((const float4*)in)[i];
    uint2 o;
    o.x = (unsigned)f2bf(v.x) | ((unsigned)f2bf(v.y) << 16);
    o.y = (unsigned)f2bf(v.z) | ((unsigned)f2bf(v.w) << 16);
    ((uint2*)out)[i] = o;
}

// ---------------------------------------------------------------------------
// bf16 MFMA GEMM, 128x128 tile, BK=64 double-buffered 2-phase pipeline.
// LDS XOR swizzle (both-sides). M,N mult of 128, K mult of 64*gridDim.z.
// Split-K via gridDim.z: each z-slice computes K/gridDim.z and (EPI 0) writes
// its own fp32 partial slab at Cout + z*M*ldc.  gridDim.z==1 -> plain GEMM.
// EPI 0: fp32 C.  EPI 1: bf16 C.  EPI 3: bf16 softplus(acc+bias[col]).
// ---------------------------------------------------------------------------
template<int EPI>
__launch_bounds__(256)
__global__ void gemm_db(const unsigned short* __restrict__ A,
                        const unsigned short* __restrict__ W,
                        void* __restrict__ Cout,
                        const float* __restrict__ bias,
                        int M, int N, int K, int lda, int ldb, int ldc)
{
    __shared__ unsigned short lds[2][2][128 * 64];   // 64 KB

    const int tid = threadIdx.x;
    const int l = tid & 63;
    const int w = tid >> 6;
    const int wr = w >> 1, wc = w & 1;
    const int brow = blockIdx.y * 128;
    const int bcol = blockIdx.x * 128;
    const int kloc = K / gridDim.z;                  // K-range of this slice
    const int kbeg = blockIdx.z * kloc;

    const int strow = tid >> 3;                          // 0..31
    const int scol  = ((tid & 7) ^ (strow & 7)) * 8;     // swizzled source col

    f32x4 acc[4][4];
#pragma unroll
    for (int i = 0; i < 4; ++i)
#pragma unroll
        for (int j = 0; j < 4; ++j) acc[i][j] = (f32x4)0.f;

    auto stage = [&](int bb, int k0) {
#pragma unroll
        for (int i = 0; i < 4; ++i) {
            const unsigned short* ga = A + (size_t)(brow + i * 32 + strow) * lda + k0 + scol;
            __builtin_amdgcn_global_load_lds(GLB_PTR(ga),
                LDS_PTR((char*)&lds[bb][0][0] + (i * 32 + w * 8) * 128), 16, 0, 0);
            const unsigned short* gb = W + (size_t)(bcol + i * 32 + strow) * ldb + k0 + scol;
            __builtin_amdgcn_global_load_lds(GLB_PTR(gb),
                LDS_PTR((char*)&lds[bb][1][0] + (i * 32 + w * 8) * 128), 16, 0, 0);
        }
    };

    auto compute = [&](int bb) {
        const char* baseA = (const char*)&lds[bb][0][0];
        const char* baseB = (const char*)&lds[bb][1][0];
        const int xo  = (l & 7) * 16;
        const int ko0 = (l >> 4) * 16;
#pragma unroll
        for (int ks = 0; ks < 2; ++ks) {
            const int kb = ks * 64 + ko0;
            short8 af[4], bfr[4];
#pragma unroll
            for (int i = 0; i < 4; ++i) {
                const int rowA = wr * 64 + i * 16 + (l & 15);
                af[i] = *(const short8*)(baseA + rowA * 128 + (kb ^ xo));
                const int rowB = wc * 64 + i * 16 + (l & 15);
                bfr[i] = *(const short8*)(baseB + rowB * 128 + (kb ^ xo));
            }
#pragma unroll
            for (int i = 0; i < 4; ++i)
#pragma unroll
                for (int j = 0; j < 4; ++j)
                    acc[i][j] = __builtin_amdgcn_mfma_f32_16x16x32_bf16(af[i], bfr[j], acc[i][j], 0, 0, 0);
        }
    };

    const int nt = kloc / 64;
    stage(0, kbeg);
    __syncthreads();
    int cur = 0;
    for (int t = 0; t < nt - 1; ++t) {
        stage(cur ^ 1, kbeg + (t + 1) * 64);
        compute(cur);
        __syncthreads();
        cur ^= 1;
    }
    compute(cur);

#pragma unroll
    for (int i = 0; i < 4; ++i) {
        const int row0 = brow + wr * 64 + i * 16 + ((l >> 4) * 4);
#pragma unroll
        for (int j = 0; j < 4; ++j) {
            const int col = bcol + wc * 64 + j * 16 + (l & 15);
            if (EPI == 1) {
                unsigned short* Cb = (unsigned short*)Cout;
#pragma unroll
                for (int r = 0; r < 4; ++r)
                    Cb[(size_t)(row0 + r) * ldc + col] = f2bf(acc[i][j][r]);
            } else if (EPI == 3) {
                const float bv = bias[col];
#pragma unroll
                for (int r = 0; r < 4; ++r) {
                    float v = acc[i][j][r] + bv;
                    v = (v > 20.f) ? v : log1pf(__expf(v));
                    ((unsigned short*)Cout)[(size_t)(row0 + r) * ldc + col] = f2bf(v);
                }
            } else {
                float* Cf = (float*)Cout + (size_t)blockIdx.z * M * ldc;
#pragma unroll
                for (int r = 0; r < 4; ++r)
                    Cf[(size_t)(row0 + r) * ldc + col] = acc[i][j][r];
            }
        }
    }
}

// sum 2 fp32 partial slabs -> out (float4)
__launch_bounds__(256)
__global__ void add2(const float* __restrict__ part, float* __restrict__ out, int n4)
{
    int i = blockIdx.x * 256 + threadIdx.x;
    if (i < n4) {
        float4 a = ((const float4*)part)[i];
        float4 b = ((const float4*)part)[(size_t)n4 + i];
        a.x += b.x; a.y += b.y; a.z += b.z; a.w += b.w;
        ((float4*)out)[i] = a;
    }
}

// ---------------------------------------------------------------------------
// Split-K MFMA GEMM for x_proj (N=96): blockIdx.z = k-slice, partial C out.
// ---------------------------------------------------------------------------
__launch_bounds__(256)
__global__ void gemm_mfma_sk(const unsigned short* __restrict__ A,
                             const unsigned short* __restrict__ W,
                             float* __restrict__ Cpart,
                             int M, int N, int K, int lda, int ldb, int ldc, int kslices)
{
    __shared__ unsigned short Asub[128 * 32];
    __shared__ unsigned short Bsub[128 * 32];

    const int tid = threadIdx.x;
    const int l = tid & 63;
    const int w = tid >> 6;
    const int wr = w >> 1, wc = w & 1;
    const int brow = blockIdx.y * 128;
    const int bcol = blockIdx.x * 128;
    const int ks = blockIdx.z;
    const int klen = K / kslices;
    const int kbeg = ks * klen;
    float* C = Cpart + (size_t)ks * M * ldc;

    f32x4 acc[4][4];
#pragma unroll
    for (int i = 0; i < 4; ++i)
#pragma unroll
        for (int j = 0; j < 4; ++j) acc[i][j] = (f32x4)0.f;

    const int srow = tid >> 2;
    const int scol = (tid & 3) * 8;

    for (int k0 = kbeg; k0 < kbeg + klen; k0 += 32) {
#pragma unroll
        for (int i = 0; i < 2; ++i) {
            const int ar = brow + i * 64 + srow;
            const unsigned short* ga = A + (size_t)ar * lda + k0 + scol;
            __builtin_amdgcn_global_load_lds(GLB_PTR(ga),
                LDS_PTR((char*)Asub + i * 4096 + w * 1024), 16, 0, 0);
            int nr = bcol + i * 64 + srow;
            if (nr > N - 1) nr = N - 1;
            const unsigned short* gb = W + (size_t)nr * ldb + k0 + scol;
            __builtin_amdgcn_global_load_lds(GLB_PTR(gb),
                LDS_PTR((char*)Bsub + i * 4096 + w * 1024), 16, 0, 0);
        }
        __syncthreads();

        short8 af[4], bf[4];
#pragma unroll
        for (int i = 0; i < 4; ++i) {
            const int row = wr * 64 + i * 16 + (l & 15);
            af[i] = *(const short8*)((const char*)Asub + row * 64 + (l >> 4) * 16);
        }
#pragma unroll
        for (int j = 0; j < 4; ++j) {
            const int row = wc * 64 + j * 16 + (l & 15);
            bf[j] = *(const short8*)((const char*)Bsub + row * 64 + (l >> 4) * 16);
        }
#pragma unroll
        for (int i = 0; i < 4; ++i)
#pragma unroll
            for (int j = 0; j < 4; ++j)
                acc[i][j] = __builtin_amdgcn_mfma_f32_16x16x32_bf16(af[i], bf[j], acc[i][j], 0, 0, 0);
        __syncthreads();
    }

#pragma unroll
    for (int i = 0; i < 4; ++i) {
        const int row0 = brow + wr * 64 + i * 16 + ((l >> 4) * 4);
#pragma unroll
        for (int j = 0; j < 4; ++j) {
            const int col = bcol + wc * 64 + j * 16 + (l & 15);
            if (col < N) {
#pragma unroll
                for (int r = 0; r < 4; ++r)
                    C[(size_t)(row0 + r) * ldc + col] = acc[i][j][r];
            }
        }
    }
}

// sum partial slices -> xdbl (fp32) + compact bf16 copy of dt cols [0,64)
__launch_bounds__(256)
__global__ void sk_reduce(const float* __restrict__ part, float* __restrict__ out,
                          unsigned short* __restrict__ dtb, int n4, int slices)
{
    int i = blockIdx.x * 256 + threadIdx.x;
    if (i < n4) {
        float4 s = ((const float4*)part)[i];
        for (int k = 1; k < slices; ++k) {
            float4 p = ((const float4*)part)[(size_t)k * n4 + i];
            s.x += p.x; s.y += p.y; s.z += p.z; s.w += p.w;
        }
        ((float4*)out)[i] = s;
        const int r = i / 24, cq = i % 24;
        if (cq < 16) {
            uint2 o;
            o.x = (unsigned)f2bf(s.x) | ((unsigned)f2bf(s.y) << 16);
            o.y = (unsigned)f2bf(s.z) | ((unsigned)f2bf(s.w) << 16);
            *(uint2*)&dtb[(size_t)r * DTR + cq * 4] = o;
        }
    }
}

// ---------------------------------------------------------------------------
// Causal depthwise conv1d (width 4) + bias + silu.  bf16 in/out.
// ---------------------------------------------------------------------------
__launch_bounds__(256)
__global__ void conv_silu_kernel(const unsigned short* __restrict__ xzb,
                                 const float* __restrict__ cw,
                                 const float* __restrict__ cb,
                                 unsigned short* __restrict__ ub)
{
    const int orig = blockIdx.x;
    const int bl = (orig & 7) * (BLTOK / 8) + (orig >> 3);   // bijective (4096%8==0)
    const int l  = bl & (LSEQ - 1);
    const int d0 = threadIdx.x * 8;

    float acc[8];
    float4 w4[8];
#pragma unroll
    for (int q = 0; q < 8; ++q) {
        w4[q]  = *(const float4*)&cw[(d0 + q) * 4];
        acc[q] = cb[d0 + q];
    }
#pragma unroll
    for (int k = 0; k < 4; ++k) {
        const int ls = l - 3 + k;
        if (ls < 0) continue;
        short8 v = *(const short8*)&xzb[(size_t)(bl - 3 + k) * (2 * DI) + d0];
#pragma unroll
        for (int q = 0; q < 8; ++q) {
            const float wk = ((const float*)&w4[q])[k];
            acc[q] = fmaf(wk, bf2f((unsigned short)v[q]), acc[q]);
        }
    }
    short8 o;
#pragma unroll
    for (int q = 0; q < 8; ++q) {
        const float s = acc[q] / (1.f + __expf(-acc[q]));
        o[q] = (short)f2bf(s);
    }
    *(short8*)&ub[(size_t)bl * DI + d0] = o;
}

// ---------------------------------------------------------------------------
// Scan phase 1: per chunk, per (b,d): 16 n-states in registers.
// delta bf16; S4D fast path (dA[n] = w^(n+1)); stores S + dsum (no P).
// ---------------------------------------------------------------------------
__launch_bounds__(256)
__global__ void scan_phase1(const unsigned short* __restrict__ delta,
                            const unsigned short* __restrict__ ub,
                            const float* __restrict__ xdbl, const float* __restrict__ A_log,
                            float* __restrict__ S, float* __restrict__ dsum_out)
{
    __shared__ float sB[LC][NST];
    const int tid = threadIdx.x;
    const int d = blockIdx.x * 256 + tid;
    const int c = blockIdx.y;
    const int b = blockIdx.z;
    const int t0 = c * LC;

    for (int i = tid; i < LC * NST; i += 256)
        sB[i >> 4][i & 15] = xdbl[(size_t)(b * LSEQ + t0 + (i >> 4)) * 96 + 64 + (i & 15)];
    __syncthreads();

    const float Av0 = -__expf(A_log[d * NST]) * LOG2E;
    bool fast = true;
    for (int n = 1; n < NST; ++n) {
        const float avn = -__expf(A_log[d * NST + n]) * LOG2E;
        fast &= (fabsf(avn - (float)(n + 1) * Av0) <= 1e-3f * fabsf(avn));
    }

    float Sv[NST];
    float dsum = 0.f;
#pragma unroll
    for (int n = 0; n < NST; ++n) Sv[n] = 0.f;

    const unsigned short* dbase = delta + (size_t)(b * LSEQ + t0) * DI + d;
    const unsigned short* ubase = ub    + (size_t)(b * LSEQ + t0) * DI + d;

    if (fast) {
        for (int tg = 0; tg < LC; tg += 4) {
            float dl[4], uu[4];
#pragma unroll
            for (int q = 0; q < 4; ++q) {
                dl[q] = bf2f(dbase[(size_t)(tg + q) * DI]);
                uu[q] = bf2f(ubase[(size_t)(tg + q) * DI]);
            }
#pragma unroll
            for (int q = 0; q < 4; ++q) {
                const float du = dl[q] * uu[q];
                dsum += dl[q];
                float e[NST];
                pow_tree(__builtin_amdgcn_exp2f(dl[q] * Av0), e);
#pragma unroll
                for (int n = 0; n < NST; ++n)
                    Sv[n] = fmaf(e[n], Sv[n], du * sB[tg + q][n]);
            }
        }
    } else {
        for (int t = 0; t < LC; ++t) {
            const float dlt = bf2f(dbase[(size_t)t * DI]);
            const float uu  = bf2f(ubase[(size_t)t * DI]);
            const float du  = dlt * uu;
            dsum += dlt;
            for (int n = 0; n < NST; ++n) {
                const float avn = -__expf(A_log[d * NST + n]) * LOG2E;
                const float dA = __builtin_amdgcn_exp2f(dlt * avn);
                Sv[n] = fmaf(dA, Sv[n], du * sB[t][n]);
            }
        }
    }

    const size_t base = ((size_t)(b * CH + c) * DI + d) * NST;
#pragma unroll
    for (int n = 0; n < NST; n += 4)
        *(f32x4*)&S[base + n] = (f32x4){Sv[n], Sv[n+1], Sv[n+2], Sv[n+3]};
    dsum_out[(size_t)(b * CH + c) * DI + d] = dsum;
}

// ---------------------------------------------------------------------------
// Scan phase 2: sequential combine over chunks; recompute P from dsum.
// ---------------------------------------------------------------------------
__launch_bounds__(256)
__global__ void scan_phase2(const float* __restrict__ S, const float* __restrict__ dsum,
                            const float* __restrict__ A_log, float* __restrict__ hin)
{
    const int g = blockIdx.x * 256 + threadIdx.x;
    const int n = g & 15;
    const int d = (g >> 4) & (DI - 1);
    const int b = g >> 15;
    const float avn = -__expf(A_log[d * NST + n]) * LOG2E;
    float h = 0.f;
    for (int c = 0; c < CH; ++c) {
        const size_t idx = ((size_t)(b * CH + c) * DI + d) * NST + n;
        hin[idx] = h;
        const float Pc = __builtin_amdgcn_exp2f(dsum[(size_t)(b * CH + c) * DI + d] * avn);
        h = fmaf(Pc, h, S[idx]);
    }
}

// ---------------------------------------------------------------------------
// Scan phase 3: replay chunk with h_in; fuse D-skip + silu(z) gating; bf16 out.
// ---------------------------------------------------------------------------
__launch_bounds__(256)
__global__ void scan_phase3(const unsigned short* __restrict__ delta,
                            const unsigned short* __restrict__ ub,
                            const float* __restrict__ xdbl, const float* __restrict__ A_log,
                            const float* __restrict__ Dskip, const unsigned short* __restrict__ xzb,
                            const float* __restrict__ hin, unsigned short* __restrict__ yg)
{
    __shared__ float sB[LC][NST], sC[LC][NST];
    const int tid = threadIdx.x;
    const int d = blockIdx.x * 256 + tid;
    const int c = blockIdx.y;
    const int b = blockIdx.z;
    const int t0 = c * LC;

    for (int i = tid; i < LC * NST; i += 256) {
        const size_t row = (size_t)(b * LSEQ + t0 + (i >> 4)) * 96;
        sB[i >> 4][i & 15] = xdbl[row + 64 + (i & 15)];
        sC[i >> 4][i & 15] = xdbl[row + 80 + (i & 15)];
    }
    __syncthreads();

    const float Av0 = -__expf(A_log[d * NST]) * LOG2E;
    bool fast = true;
    for (int n = 1; n < NST; ++n) {
        const float avn = -__expf(A_log[d * NST + n]) * LOG2E;
        fast &= (fabsf(avn - (float)(n + 1) * Av0) <= 1e-3f * fabsf(avn));
    }

    float h[NST];
    const size_t hbase = ((size_t)(b * CH + c) * DI + d) * NST;
#pragma unroll
    for (int n = 0; n < NST; n += 4) {
        f32x4 t = *(const f32x4*)&hin[hbase + n];
        h[n] = t.x; h[n+1] = t.y; h[n+2] = t.z; h[n+3] = t.w;
    }
    const float Dskv = Dskip[d];

    const unsigned short* dbase = delta + (size_t)(b * LSEQ + t0) * DI + d;
    const unsigned short* ubase = ub    + (size_t)(b * LSEQ + t0) * DI + d;
    const unsigned short* zbase = xzb   + (size_t)(b * LSEQ + t0) * (2 * DI) + DI + d;
    unsigned short* yrow = yg + (size_t)(b * LSEQ + t0) * DI + d;

    if (fast) {
        for (int tg = 0; tg < LC; tg += 4) {
            float dl[4], uu[4], zz[4];
#pragma unroll
            for (int q = 0; q < 4; ++q) {
                dl[q] = bf2f(dbase[(size_t)(tg + q) * DI]);
                uu[q] = bf2f(ubase[(size_t)(tg + q) * DI]);
                zz[q] = bf2f(zbase[(size_t)(tg + q) * (2 * DI)]);
            }
#pragma unroll
            for (int q = 0; q < 4; ++q) {
                const float du = dl[q] * uu[q];
                float e[NST];
                pow_tree(__builtin_amdgcn_exp2f(dl[q] * Av0), e);
                float y = 0.f;
#pragma unroll
                for (int n = 0; n < NST; ++n) {
                    h[n] = fmaf(e[n], h[n], du * sB[tg + q][n]);
                    y = fmaf(h[n], sC[tg + q][n], y);
                }
                const float zv = zz[q];
                const float sig = __frcp_rn(1.f + __expf(-zv));
                const float val = (y + uu[q] * Dskv) * (zv * sig);
                yrow[(size_t)(tg + q) * DI] = f2bf(val);
            }
        }
    } else {
        for (int t = 0; t < LC; ++t) {
            const float dlt = bf2f(dbase[(size_t)t * DI]);
            const float uu  = bf2f(ubase[(size_t)t * DI]);
            const float zv  = bf2f(zbase[(size_t)t * (2 * DI)]);
            const float du  = dlt * uu;
            float y = 0.f;
            for (int n = 0; n < NST; ++n) {
                const float avn = -__expf(A_log[d * NST + n]) * LOG2E;
                const float dA = __builtin_amdgcn_exp2f(dlt * avn);
                h[n] = fmaf(dA, h[n], du * sB[t][n]);
                y = fmaf(h[n], sC[t][n], y);
            }
            const float sig = __frcp_rn(1.f + __expf(-zv));
            const float val = (y + uu * Dskv) * (zv * sig);
            yrow[(size_t)t * DI] = f2bf(val);
        }
    }
}

// ---------------------------------------------------------------------------
extern "C" void kernel_launch(void* const* d_in, const int* in_sizes, int n_in,
                              void* d_out, int out_size, void* d_ws, size_t ws_size,
                              hipStream_t stream)
{
    const float* x        = (const float*)d_in[0];
    const float* in_w     = (const float*)d_in[1];
    const float* conv_w   = (const float*)d_in[2];
    const float* conv_b   = (const float*)d_in[3];
    const float* xproj_w  = (const float*)d_in[4];
    const float* dtproj_w = (const float*)d_in[5];
    const float* dtproj_b = (const float*)d_in[6];
    const float* A_log    = (const float*)d_in[7];
    const float* Dskip    = (const float*)d_in[8];
    const float* out_w    = (const float*)d_in[9];
    float* out = (float*)d_out;

    char* ws = (char*)d_ws;
#define MB(x) ((size_t)(x) * 1024 * 1024)
    unsigned short* xzb   = (unsigned short*)(ws);           // bf16 [4096,4096] 32 MB
    unsigned short* ub    = (unsigned short*)(ws + MB(32));  // bf16 [4096,2048] 16 MB
    unsigned short* delta = (unsigned short*)(ws + MB(48));  // bf16 [4096,2048] 16 MB
    float*          xdbl  = (float*)(ws + MB(64));           // fp32 [4096,96]  1.5 MB
    unsigned short* ygb   = (unsigned short*)(ws + MB(66));  // bf16 [4096,2048] 16 MB
    float*          S     = (float*)(ws + MB(82));           // 16 MB (also x_proj partials)
    float*          dsum  = (float*)(ws + MB(98));           // 1 MB
    float*          hin   = (float*)(ws + MB(99));           // 16 MB
    unsigned short* xb    = (unsigned short*)(ws + MB(115)); // bf16 x      8 MB
    unsigned short* wb1   = (unsigned short*)(ws + MB(123)); // bf16 in_w   8 MB
    unsigned short* wb3   = (unsigned short*)(ws + MB(131)); // bf16 xproj  0.4 MB
    unsigned short* wb6   = (unsigned short*)(ws + MB(132)); // bf16 out_w  4 MB
    unsigned short* wb5   = (unsigned short*)(ws + MB(136)); // bf16 dtproj_w 0.25 MB
    unsigned short* dtb   = (unsigned short*)(ws + MB(137)); // bf16 dt [4096,64] 0.5 MB
    float*          opart = (float*)(ws + MB(140));          // 2 x [4096,1024] fp32 = 32 MB
    float*          xdbl_part = S;                           // 8 x [4096,96]

    dim3 blk(256);

    // 0) all fp32->bf16 casts in one launch
    cast_all<<<dim3((C4_TOT + 255) / 256), blk, 0, stream>>>(x, xb, in_w, wb1, xproj_w, wb3,
                                                             out_w, wb6, dtproj_w, wb5);

    // 1) in_proj: xzb = bf16(x @ in_w^T)   [4096 x 4096], K=1024
    gemm_db<1><<<dim3(32, 32), blk, 0, stream>>>(xb, wb1, xzb, nullptr,
                                                 BLTOK, 2 * DI, DM, DM, DM, 2 * DI);

    // 2) conv + silu -> ub (bf16)
    conv_silu_kernel<<<dim3(BLTOK), blk, 0, stream>>>(xzb, conv_w, conv_b, ub);

    // 3) x_proj split-K=8: partials then reduce (fp32 xdbl + bf16 dt copy)
    gemm_mfma_sk<<<dim3(1, 32, 8), blk, 0, stream>>>(ub, wb3, xdbl_part,
                                                     BLTOK, DTR + 2 * NST, DI, DI, DI, 96, 8);
    sk_reduce<<<dim3((BLTOK * 96 / 4 + 255) / 256), blk, 0, stream>>>(xdbl_part, xdbl, dtb,
                                                                      BLTOK * 96 / 4, 8);

    // 4) dt_proj + softplus -> bf16 delta  [4096 x 2048], K=64 (MFMA)
    gemm_db<3><<<dim3(16, 32), blk, 0, stream>>>(dtb, wb5, delta, dtproj_b,
                                                 BLTOK, DI, DTR, DTR, DTR, DI);

    // 5) chunked selective scan (CH=64, LC=32; P replaced by dsum)
    scan_phase1<<<dim3(DI / 256, CH, NB), blk, 0, stream>>>(delta, ub, xdbl, A_log, S, dsum);
    scan_phase2<<<dim3(NB * DI * NST / 256), blk, 0, stream>>>(S, dsum, A_log, hin);
    scan_phase3<<<dim3(DI / 256, CH, NB), blk, 0, stream>>>(delta, ub, xdbl, A_log, Dskip,
                                                            xzb, hin, ygb);

    // 6) out_proj: split-K=2 partials (512 blocks) then add  [4096 x 1024], K=2048
    gemm_db<0><<<dim3(8, 32, 2), blk, 0, stream>>>(ygb, wb6, opart, nullptr,
                                                   BLTOK, DM, DI, DI, DI, DM);
    add2<<<dim3((BLTOK * DM / 4 + 255) / 256), blk, 0, stream>>>(opart, out, BLTOK * DM / 4);
}

// Round 10
// 216.228 us; speedup vs baseline: 1.0748x; 1.0586x over previous
//
#include <hip/hip_runtime.h>
#include <hip/hip_bf16.h>
#include <math.h>

// Problem constants (MambaBlock: D_MODEL=1024, D_STATE=16, D_CONV=4, EXPAND=2, DT_RANK=64)
#define NB      2
#define LSEQ    2048
#define BLTOK   4096      // NB * LSEQ
#define DM      1024
#define DI      2048      // EXPAND * DM
#define NST     16
#define DTR     64
#define CH      64        // scan chunks
#define LC      32        // LSEQ / CH
#define LOG2E   1.44269504f

typedef __attribute__((ext_vector_type(8))) short short8;
typedef __attribute__((ext_vector_type(4))) float f32x4;

#define LDS_PTR(p) ((__attribute__((address_space(3))) void*)(p))
#define GLB_PTR(p) ((const __attribute__((address_space(1))) void*)(p))

static __device__ __forceinline__ unsigned short f2bf(float f) {
    unsigned int u = __float_as_uint(f);
    unsigned int r = (u + 0x7FFFu + ((u >> 16) & 1u)) >> 16;   // RNE
    return (unsigned short)r;
}
static __device__ __forceinline__ float bf2f(unsigned short v) {
    return __uint_as_float((unsigned int)v << 16);
}

// w^(n+1) for n=0..15 via binary tree (depth 4, 15 full-rate muls)
static __device__ __forceinline__ void pow_tree(float w, float* e) {
    e[0]  = w;
    e[1]  = e[0] * e[0];
    e[2]  = e[1] * e[0];
    e[3]  = e[1] * e[1];
    e[4]  = e[3] * e[0];
    e[5]  = e[3] * e[1];
    e[6]  = e[3] * e[2];
    e[7]  = e[3] * e[3];
    e[8]  = e[7] * e[0];
    e[9]  = e[7] * e[1];
    e[10] = e[7] * e[2];
    e[11] = e[7] * e[3];
    e[12] = e[7] * e[4];
    e[13] = e[7] * e[5];
    e[14] = e[7] * e[6];
    e[15] = e[7] * e[7];
}

// ---------------------------------------------------------------------------
// Fused fp32 -> bf16 cast of all 5 weight/activation tensors (one launch).
// ---------------------------------------------------------------------------
#define C4_X   (BLTOK * DM / 4)
#define C4_W1  (2 * DI * DM / 4)
#define C4_W3  (96 * DI / 4)
#define C4_W6  (DM * DI / 4)
#define C4_W5  (DI * DTR / 4)
#define C4_TOT (C4_X + C4_W1 + C4_W3 + C4_W6 + C4_W5)

__launch_bounds__(256)
__global__ void cast_all(const float* __restrict__ x,   unsigned short* __restrict__ xb,
                         const float* __restrict__ w1,  unsigned short* __restrict__ wb1,
                         const float* __restrict__ w3,  unsigned short* __restrict__ wb3,
                         const float* __restrict__ w6,  unsigned short* __restrict__ wb6,
                         const float* __restrict__ w5,  unsigned short* __restrict__ wb5)
{
    int i = blockIdx.x * 256 + threadIdx.x;
    if (i >= C4_TOT) return;
    const float* in; unsigned short* out;
    if (i < C4_X)                         { in = x;  out = xb;  }
    else if ((i -= C4_X) < C4_W1)         { in = w1; out = wb1; }
    else if ((i -= C4_W1) < C4_W3)        { in = w3; out = wb3; }
    else if ((i -= C4_W3) < C4_W6)        { in = w6; out = wb6; }
    else       { i -= C4_W6;                in = w5; out = wb5; }
    float4 v = ((const float4*)in)[i];
    uint2 o;
    o.x = (unsigned)f2bf(v.x) | ((unsigned)f2bf(v.y) << 16);
    o.y = (unsigned)f2bf(v.z) | ((unsigned)f2bf(v.w) << 16);
    ((uint2*)out)[i] = o;
}

// ---------------------------------------------------------------------------
// bf16 MFMA GEMM, 128x128 tile, BK=64 double-buffered 2-phase pipeline.
// LDS XOR swizzle (both-sides). M,N mult of 128, K mult of 64.
// EPI 0: fp32 C.  EPI 1: bf16 C.  EPI 3: bf16 softplus(acc+bias[col]).
// ---------------------------------------------------------------------------
template<int EPI>
__launch_bounds__(256)
__global__ void gemm_db(const unsigned short* __restrict__ A,
                        const unsigned short* __restrict__ W,
                        void* __restrict__ Cout,
                        const float* __restrict__ bias,
                        int M, int N, int K, int lda, int ldb, int ldc)
{
    __shared__ unsigned short lds[2][2][128 * 64];   // 64 KB

    const int tid = threadIdx.x;
    const int l = tid & 63;
    const int w = tid >> 6;
    const int wr = w >> 1, wc = w & 1;
    const int brow = blockIdx.y * 128;
    const int bcol = blockIdx.x * 128;

    const int strow = tid >> 3;                          // 0..31
    const int scol  = ((tid & 7) ^ (strow & 7)) * 8;     // swizzled source col

    f32x4 acc[4][4];
#pragma unroll
    for (int i = 0; i < 4; ++i)
#pragma unroll
        for (int j = 0; j < 4; ++j) acc[i][j] = (f32x4)0.f;

    auto stage = [&](int bb, int k0) {
#pragma unroll
        for (int i = 0; i < 4; ++i) {
            const unsigned short* ga = A + (size_t)(brow + i * 32 + strow) * lda + k0 + scol;
            __builtin_amdgcn_global_load_lds(GLB_PTR(ga),
                LDS_PTR((char*)&lds[bb][0][0] + (i * 32 + w * 8) * 128), 16, 0, 0);
            const unsigned short* gb = W + (size_t)(bcol + i * 32 + strow) * ldb + k0 + scol;
            __builtin_amdgcn_global_load_lds(GLB_PTR(gb),
                LDS_PTR((char*)&lds[bb][1][0] + (i * 32 + w * 8) * 128), 16, 0, 0);
        }
    };

    auto compute = [&](int bb) {
        const char* baseA = (const char*)&lds[bb][0][0];
        const char* baseB = (const char*)&lds[bb][1][0];
        const int xo  = (l & 7) * 16;
        const int ko0 = (l >> 4) * 16;
#pragma unroll
        for (int ks = 0; ks < 2; ++ks) {
            const int kb = ks * 64 + ko0;
            short8 af[4], bfr[4];
#pragma unroll
            for (int i = 0; i < 4; ++i) {
                const int rowA = wr * 64 + i * 16 + (l & 15);
                af[i] = *(const short8*)(baseA + rowA * 128 + (kb ^ xo));
                const int rowB = wc * 64 + i * 16 + (l & 15);
                bfr[i] = *(const short8*)(baseB + rowB * 128 + (kb ^ xo));
            }
#pragma unroll
            for (int i = 0; i < 4; ++i)
#pragma unroll
                for (int j = 0; j < 4; ++j)
                    acc[i][j] = __builtin_amdgcn_mfma_f32_16x16x32_bf16(af[i], bfr[j], acc[i][j], 0, 0, 0);
        }
    };

    const int nt = K / 64;
    stage(0, 0);
    __syncthreads();
    int cur = 0;
    for (int t = 0; t < nt - 1; ++t) {
        stage(cur ^ 1, (t + 1) * 64);
        compute(cur);
        __syncthreads();
        cur ^= 1;
    }
    compute(cur);

#pragma unroll
    for (int i = 0; i < 4; ++i) {
        const int row0 = brow + wr * 64 + i * 16 + ((l >> 4) * 4);
#pragma unroll
        for (int j = 0; j < 4; ++j) {
            const int col = bcol + wc * 64 + j * 16 + (l & 15);
            if (EPI == 1) {
                unsigned short* Cb = (unsigned short*)Cout;
#pragma unroll
                for (int r = 0; r < 4; ++r)
                    Cb[(size_t)(row0 + r) * ldc + col] = f2bf(acc[i][j][r]);
            } else if (EPI == 3) {
                const float bv = bias[col];
#pragma unroll
                for (int r = 0; r < 4; ++r) {
                    float v = acc[i][j][r] + bv;
                    v = (v > 20.f) ? v : log1pf(__expf(v));
                    ((unsigned short*)Cout)[(size_t)(row0 + r) * ldc + col] = f2bf(v);
                }
            } else {
                float* Cf = (float*)Cout;
#pragma unroll
                for (int r = 0; r < 4; ++r)
                    Cf[(size_t)(row0 + r) * ldc + col] = acc[i][j][r];
            }
        }
    }
}

// ---------------------------------------------------------------------------
// Split-K MFMA GEMM for x_proj (N=96): blockIdx.z = k-slice, partial C out.
// ---------------------------------------------------------------------------
__launch_bounds__(256)
__global__ void gemm_mfma_sk(const unsigned short* __restrict__ A,
                             const unsigned short* __restrict__ W,
                             float* __restrict__ Cpart,
                             int M, int N, int K, int lda, int ldb, int ldc, int kslices)
{
    __shared__ unsigned short Asub[128 * 32];
    __shared__ unsigned short Bsub[128 * 32];

    const int tid = threadIdx.x;
    const int l = tid & 63;
    const int w = tid >> 6;
    const int wr = w >> 1, wc = w & 1;
    const int brow = blockIdx.y * 128;
    const int bcol = blockIdx.x * 128;
    const int ks = blockIdx.z;
    const int klen = K / kslices;
    const int kbeg = ks * klen;
    float* C = Cpart + (size_t)ks * M * ldc;

    f32x4 acc[4][4];
#pragma unroll
    for (int i = 0; i < 4; ++i)
#pragma unroll
        for (int j = 0; j < 4; ++j) acc[i][j] = (f32x4)0.f;

    const int srow = tid >> 2;
    const int scol = (tid & 3) * 8;

    for (int k0 = kbeg; k0 < kbeg + klen; k0 += 32) {
#pragma unroll
        for (int i = 0; i < 2; ++i) {
            const int ar = brow + i * 64 + srow;
            const unsigned short* ga = A + (size_t)ar * lda + k0 + scol;
            __builtin_amdgcn_global_load_lds(GLB_PTR(ga),
                LDS_PTR((char*)Asub + i * 4096 + w * 1024), 16, 0, 0);
            int nr = bcol + i * 64 + srow;
            if (nr > N - 1) nr = N - 1;
            const unsigned short* gb = W + (size_t)nr * ldb + k0 + scol;
            __builtin_amdgcn_global_load_lds(GLB_PTR(gb),
                LDS_PTR((char*)Bsub + i * 4096 + w * 1024), 16, 0, 0);
        }
        __syncthreads();

        short8 af[4], bf[4];
#pragma unroll
        for (int i = 0; i < 4; ++i) {
            const int row = wr * 64 + i * 16 + (l & 15);
            af[i] = *(const short8*)((const char*)Asub + row * 64 + (l >> 4) * 16);
        }
#pragma unroll
        for (int j = 0; j < 4; ++j) {
            const int row = wc * 64 + j * 16 + (l & 15);
            bf[j] = *(const short8*)((const char*)Bsub + row * 64 + (l >> 4) * 16);
        }
#pragma unroll
        for (int i = 0; i < 4; ++i)
#pragma unroll
            for (int j = 0; j < 4; ++j)
                acc[i][j] = __builtin_amdgcn_mfma_f32_16x16x32_bf16(af[i], bf[j], acc[i][j], 0, 0, 0);
        __syncthreads();
    }

#pragma unroll
    for (int i = 0; i < 4; ++i) {
        const int row0 = brow + wr * 64 + i * 16 + ((l >> 4) * 4);
#pragma unroll
        for (int j = 0; j < 4; ++j) {
            const int col = bcol + wc * 64 + j * 16 + (l & 15);
            if (col < N) {
#pragma unroll
                for (int r = 0; r < 4; ++r)
                    C[(size_t)(row0 + r) * ldc + col] = acc[i][j][r];
            }
        }
    }
}

// sum partial slices -> xdbl (fp32) + compact bf16 copy of dt cols [0,64)
__launch_bounds__(256)
__global__ void sk_reduce(const float* __restrict__ part, float* __restrict__ out,
                          unsigned short* __restrict__ dtb, int n4, int slices)
{
    int i = blockIdx.x * 256 + threadIdx.x;
    if (i < n4) {
        float4 s = ((const float4*)part)[i];
        for (int k = 1; k < slices; ++k) {
            float4 p = ((const float4*)part)[(size_t)k * n4 + i];
            s.x += p.x; s.y += p.y; s.z += p.z; s.w += p.w;
        }
        ((float4*)out)[i] = s;
        const int r = i / 24, cq = i % 24;
        if (cq < 16) {
            uint2 o;
            o.x = (unsigned)f2bf(s.x) | ((unsigned)f2bf(s.y) << 16);
            o.y = (unsigned)f2bf(s.z) | ((unsigned)f2bf(s.w) << 16);
            *(uint2*)&dtb[(size_t)r * DTR + cq * 4] = o;
        }
    }
}

// ---------------------------------------------------------------------------
// Causal depthwise conv1d (width 4) + bias + silu.  bf16 in/out.
// ---------------------------------------------------------------------------
__launch_bounds__(256)
__global__ void conv_silu_kernel(const unsigned short* __restrict__ xzb,
                                 const float* __restrict__ cw,
                                 const float* __restrict__ cb,
                                 unsigned short* __restrict__ ub)
{
    const int orig = blockIdx.x;
    const int bl = (orig & 7) * (BLTOK / 8) + (orig >> 3);   // bijective (4096%8==0)
    const int l  = bl & (LSEQ - 1);
    const int d0 = threadIdx.x * 8;

    float acc[8];
    float4 w4[8];
#pragma unroll
    for (int q = 0; q < 8; ++q) {
        w4[q]  = *(const float4*)&cw[(d0 + q) * 4];
        acc[q] = cb[d0 + q];
    }
#pragma unroll
    for (int k = 0; k < 4; ++k) {
        const int ls = l - 3 + k;
        if (ls < 0) continue;
        short8 v = *(const short8*)&xzb[(size_t)(bl - 3 + k) * (2 * DI) + d0];
#pragma unroll
        for (int q = 0; q < 8; ++q) {
            const float wk = ((const float*)&w4[q])[k];
            acc[q] = fmaf(wk, bf2f((unsigned short)v[q]), acc[q]);
        }
    }
    short8 o;
#pragma unroll
    for (int q = 0; q < 8; ++q) {
        const float s = acc[q] / (1.f + __expf(-acc[q]));
        o[q] = (short)f2bf(s);
    }
    *(short8*)&ub[(size_t)bl * DI + d0] = o;
}

// ---------------------------------------------------------------------------
// Scan phase 1: per chunk, per (b,d): 16 n-states in registers.
// delta bf16; S4D fast path (dA[n] = w^(n+1)); stores S (bf16) + dsum.
// ---------------------------------------------------------------------------
__launch_bounds__(256)
__global__ void scan_phase1(const unsigned short* __restrict__ delta,
                            const unsigned short* __restrict__ ub,
                            const float* __restrict__ xdbl, const float* __restrict__ A_log,
                            unsigned short* __restrict__ S, float* __restrict__ dsum_out)
{
    __shared__ float sB[LC][NST];
    const int tid = threadIdx.x;
    const int d = blockIdx.x * 256 + tid;
    const int c = blockIdx.y;
    const int b = blockIdx.z;
    const int t0 = c * LC;

    for (int i = tid; i < LC * NST; i += 256)
        sB[i >> 4][i & 15] = xdbl[(size_t)(b * LSEQ + t0 + (i >> 4)) * 96 + 64 + (i & 15)];
    __syncthreads();

    const float Av0 = -__expf(A_log[d * NST]) * LOG2E;
    bool fast = true;
    for (int n = 1; n < NST; ++n) {
        const float avn = -__expf(A_log[d * NST + n]) * LOG2E;
        fast &= (fabsf(avn - (float)(n + 1) * Av0) <= 1e-3f * fabsf(avn));
    }

    float Sv[NST];
    float dsum = 0.f;
#pragma unroll
    for (int n = 0; n < NST; ++n) Sv[n] = 0.f;

    const unsigned short* dbase = delta + (size_t)(b * LSEQ + t0) * DI + d;
    const unsigned short* ubase = ub    + (size_t)(b * LSEQ + t0) * DI + d;

    if (fast) {
        for (int tg = 0; tg < LC; tg += 4) {
            float dl[4], uu[4];
#pragma unroll
            for (int q = 0; q < 4; ++q) {
                dl[q] = bf2f(dbase[(size_t)(tg + q) * DI]);
                uu[q] = bf2f(ubase[(size_t)(tg + q) * DI]);
            }
#pragma unroll
            for (int q = 0; q < 4; ++q) {
                const float du = dl[q] * uu[q];
                dsum += dl[q];
                float e[NST];
                pow_tree(__builtin_amdgcn_exp2f(dl[q] * Av0), e);
#pragma unroll
                for (int n = 0; n < NST; ++n)
                    Sv[n] = fmaf(e[n], Sv[n], du * sB[tg + q][n]);
            }
        }
    } else {
        for (int t = 0; t < LC; ++t) {
            const float dlt = bf2f(dbase[(size_t)t * DI]);
            const float uu  = bf2f(ubase[(size_t)t * DI]);
            const float du  = dlt * uu;
            dsum += dlt;
            for (int n = 0; n < NST; ++n) {
                const float avn = -__expf(A_log[d * NST + n]) * LOG2E;
                const float dA = __builtin_amdgcn_exp2f(dlt * avn);
                Sv[n] = fmaf(dA, Sv[n], du * sB[t][n]);
            }
        }
    }

    const size_t base = ((size_t)(b * CH + c) * DI + d) * NST;
    short8 s0, s1;
#pragma unroll
    for (int n = 0; n < 8; ++n) { s0[n] = (short)f2bf(Sv[n]); s1[n] = (short)f2bf(Sv[8 + n]); }
    *(short8*)&S[base]     = s0;
    *(short8*)&S[base + 8] = s1;
    dsum_out[(size_t)(b * CH + c) * DI + d] = dsum;
}

// ---------------------------------------------------------------------------
// Scan phase 2: sequential combine over chunks (fp32 register chain);
// recompute P from dsum; bf16 S in, bf16 hin out.
// ---------------------------------------------------------------------------
__launch_bounds__(256)
__global__ void scan_phase2(const unsigned short* __restrict__ S, const float* __restrict__ dsum,
                            const float* __restrict__ A_log, unsigned short* __restrict__ hin)
{
    const int g = blockIdx.x * 256 + threadIdx.x;
    const int n = g & 15;
    const int d = (g >> 4) & (DI - 1);
    const int b = g >> 15;
    const float avn = -__expf(A_log[d * NST + n]) * LOG2E;
    float h = 0.f;
    for (int c = 0; c < CH; ++c) {
        const size_t idx = ((size_t)(b * CH + c) * DI + d) * NST + n;
        hin[idx] = f2bf(h);
        const float Pc = __builtin_amdgcn_exp2f(dsum[(size_t)(b * CH + c) * DI + d] * avn);
        h = fmaf(Pc, h, bf2f(S[idx]));
    }
}

// ---------------------------------------------------------------------------
// Scan phase 3: replay chunk with h_in (bf16); fuse D-skip + silu(z) gating.
// ---------------------------------------------------------------------------
__launch_bounds__(256)
__global__ void scan_phase3(const unsigned short* __restrict__ delta,
                            const unsigned short* __restrict__ ub,
                            const float* __restrict__ xdbl, const float* __restrict__ A_log,
                            const float* __restrict__ Dskip, const unsigned short* __restrict__ xzb,
                            const unsigned short* __restrict__ hin, unsigned short* __restrict__ yg)
{
    __shared__ float sB[LC][NST], sC[LC][NST];
    const int tid = threadIdx.x;
    const int d = blockIdx.x * 256 + tid;
    const int c = blockIdx.y;
    const int b = blockIdx.z;
    const int t0 = c * LC;

    for (int i = tid; i < LC * NST; i += 256) {
        const size_t row = (size_t)(b * LSEQ + t0 + (i >> 4)) * 96;
        sB[i >> 4][i & 15] = xdbl[row + 64 + (i & 15)];
        sC[i >> 4][i & 15] = xdbl[row + 80 + (i & 15)];
    }
    __syncthreads();

    const float Av0 = -__expf(A_log[d * NST]) * LOG2E;
    bool fast = true;
    for (int n = 1; n < NST; ++n) {
        const float avn = -__expf(A_log[d * NST + n]) * LOG2E;
        fast &= (fabsf(avn - (float)(n + 1) * Av0) <= 1e-3f * fabsf(avn));
    }

    float h[NST];
    const size_t hbase = ((size_t)(b * CH + c) * DI + d) * NST;
    {
        short8 h0 = *(const short8*)&hin[hbase];
        short8 h1 = *(const short8*)&hin[hbase + 8];
#pragma unroll
        for (int n = 0; n < 8; ++n) {
            h[n]     = bf2f((unsigned short)h0[n]);
            h[8 + n] = bf2f((unsigned short)h1[n]);
        }
    }
    const float Dskv = Dskip[d];

    const unsigned short* dbase = delta + (size_t)(b * LSEQ + t0) * DI + d;
    const unsigned short* ubase = ub    + (size_t)(b * LSEQ + t0) * DI + d;
    const unsigned short* zbase = xzb   + (size_t)(b * LSEQ + t0) * (2 * DI) + DI + d;
    unsigned short* yrow = yg + (size_t)(b * LSEQ + t0) * DI + d;

    if (fast) {
        for (int tg = 0; tg < LC; tg += 4) {
            float dl[4], uu[4], zz[4];
#pragma unroll
            for (int q = 0; q < 4; ++q) {
                dl[q] = bf2f(dbase[(size_t)(tg + q) * DI]);
                uu[q] = bf2f(ubase[(size_t)(tg + q) * DI]);
                zz[q] = bf2f(zbase[(size_t)(tg + q) * (2 * DI)]);
            }
#pragma unroll
            for (int q = 0; q < 4; ++q) {
                const float du = dl[q] * uu[q];
                float e[NST];
                pow_tree(__builtin_amdgcn_exp2f(dl[q] * Av0), e);
                float y = 0.f;
#pragma unroll
                for (int n = 0; n < NST; ++n) {
                    h[n] = fmaf(e[n], h[n], du * sB[tg + q][n]);
                    y = fmaf(h[n], sC[tg + q][n], y);
                }
                const float zv = zz[q];
                const float sig = __frcp_rn(1.f + __expf(-zv));
                const float val = (y + uu[q] * Dskv) * (zv * sig);
                yrow[(size_t)(tg + q) * DI] = f2bf(val);
            }
        }
    } else {
        for (int t = 0; t < LC; ++t) {
            const float dlt = bf2f(dbase[(size_t)t * DI]);
            const float uu  = bf2f(ubase[(size_t)t * DI]);
            const float zv  = bf2f(zbase[(size_t)t * (2 * DI)]);
            const float du  = dlt * uu;
            float y = 0.f;
            for (int n = 0; n < NST; ++n) {
                const float avn = -__expf(A_log[d * NST + n]) * LOG2E;
                const float dA = __builtin_amdgcn_exp2f(dlt * avn);
                h[n] = fmaf(dA, h[n], du * sB[t][n]);
                y = fmaf(h[n], sC[t][n], y);
            }
            const float sig = __frcp_rn(1.f + __expf(-zv));
            const float val = (y + uu * Dskv) * (zv * sig);
            yrow[(size_t)t * DI] = f2bf(val);
        }
    }
}

// ---------------------------------------------------------------------------
extern "C" void kernel_launch(void* const* d_in, const int* in_sizes, int n_in,
                              void* d_out, int out_size, void* d_ws, size_t ws_size,
                              hipStream_t stream)
{
    const float* x        = (const float*)d_in[0];
    const float* in_w     = (const float*)d_in[1];
    const float* conv_w   = (const float*)d_in[2];
    const float* conv_b   = (const float*)d_in[3];
    const float* xproj_w  = (const float*)d_in[4];
    const float* dtproj_w = (const float*)d_in[5];
    const float* dtproj_b = (const float*)d_in[6];
    const float* A_log    = (const float*)d_in[7];
    const float* Dskip    = (const float*)d_in[8];
    const float* out_w    = (const float*)d_in[9];
    float* out = (float*)d_out;

    char* ws = (char*)d_ws;
#define MB(x) ((size_t)(x) * 1024 * 1024)
    unsigned short* xzb   = (unsigned short*)(ws);           // bf16 [4096,4096] 32 MB
    unsigned short* ub    = (unsigned short*)(ws + MB(32));  // bf16 [4096,2048] 16 MB
    unsigned short* delta = (unsigned short*)(ws + MB(48));  // bf16 [4096,2048] 16 MB
    float*          xdbl  = (float*)(ws + MB(64));           // fp32 [4096,96]  1.5 MB
    unsigned short* ygb   = (unsigned short*)(ws + MB(66));  // bf16 [4096,2048] 16 MB
    unsigned short* S     = (unsigned short*)(ws + MB(82));  // bf16 8 MB
    float*          dsum  = (float*)(ws + MB(90));           // 1 MB
    unsigned short* hin   = (unsigned short*)(ws + MB(91));  // bf16 8 MB
    unsigned short* xb    = (unsigned short*)(ws + MB(99));  // bf16 x      8 MB
    unsigned short* wb1   = (unsigned short*)(ws + MB(107)); // bf16 in_w   8 MB
    unsigned short* wb3   = (unsigned short*)(ws + MB(115)); // bf16 xproj  0.4 MB
    unsigned short* wb6   = (unsigned short*)(ws + MB(116)); // bf16 out_w  4 MB
    unsigned short* wb5   = (unsigned short*)(ws + MB(120)); // bf16 dtproj_w 0.25 MB
    unsigned short* dtb   = (unsigned short*)(ws + MB(121)); // bf16 dt [4096,64] 0.5 MB
    float*          xdbl_part = (float*)(ws + MB(122));      // 8 x [4096,96] fp32 = 12.6 MB

    dim3 blk(256);

    // 0) all fp32->bf16 casts in one launch
    cast_all<<<dim3((C4_TOT + 255) / 256), blk, 0, stream>>>(x, xb, in_w, wb1, xproj_w, wb3,
                                                             out_w, wb6, dtproj_w, wb5);

    // 1) in_proj: xzb = bf16(x @ in_w^T)   [4096 x 4096], K=1024
    gemm_db<1><<<dim3(32, 32), blk, 0, stream>>>(xb, wb1, xzb, nullptr,
                                                 BLTOK, 2 * DI, DM, DM, DM, 2 * DI);

    // 2) conv + silu -> ub (bf16)
    conv_silu_kernel<<<dim3(BLTOK), blk, 0, stream>>>(xzb, conv_w, conv_b, ub);

    // 3) x_proj split-K=8: partials then reduce (fp32 xdbl + bf16 dt copy)
    gemm_mfma_sk<<<dim3(1, 32, 8), blk, 0, stream>>>(ub, wb3, xdbl_part,
                                                     BLTOK, DTR + 2 * NST, DI, DI, DI, 96, 8);
    sk_reduce<<<dim3((BLTOK * 96 / 4 + 255) / 256), blk, 0, stream>>>(xdbl_part, xdbl, dtb,
                                                                      BLTOK * 96 / 4, 8);

    // 4) dt_proj + softplus -> bf16 delta  [4096 x 2048], K=64 (MFMA)
    gemm_db<3><<<dim3(16, 32), blk, 0, stream>>>(dtb, wb5, delta, dtproj_b,
                                                 BLTOK, DI, DTR, DTR, DTR, DI);

    // 5) chunked selective scan (CH=64, LC=32; bf16 S/hin, P via dsum)
    scan_phase1<<<dim3(DI / 256, CH, NB), blk, 0, stream>>>(delta, ub, xdbl, A_log, S, dsum);
    scan_phase2<<<dim3(NB * DI * NST / 256), blk, 0, stream>>>(S, dsum, A_log, hin);
    scan_phase3<<<dim3(DI / 256, CH, NB), blk, 0, stream>>>(delta, ub, xdbl, A_log, Dskip,
                                                            xzb, hin, ygb);

    // 6) out_proj: out = yg @ out_w^T   [4096 x 1024], K=2048  (plain 128x128)
    gemm_db<0><<<dim3(8, 32), blk, 0, stream>>>(ygb, wb6, out, nullptr,
                                                BLTOK, DM, DI, DI, DI, DM);
}